// Round 1
// baseline (648.711 us; speedup 1.0000x reference)
//
#include <hip/hip_runtime.h>

typedef __bf16 bf16;
typedef __bf16 bf16x4 __attribute__((ext_vector_type(4)));
typedef __bf16 bf16x8 __attribute__((ext_vector_type(8)));
typedef float  f32x4  __attribute__((ext_vector_type(4)));

// async global->LDS, 16B per lane; LDS dest is wave-uniform base + lane*16
__device__ inline void async_copy16(void* lds, const void* g) {
  __builtin_amdgcn_global_load_lds((const __attribute__((address_space(1))) void*)g,
                                   (__attribute__((address_space(3))) void*)lds,
                                   16, 0, 0);
}

// ---------------- fp32 -> bf16 convert (weights) ----------------
__global__ __launch_bounds__(256)
void f2bf_kernel(const float* __restrict__ in, bf16* __restrict__ out, int n4) {
  int i = blockIdx.x * 256 + threadIdx.x;
  if (i < n4) {
    float4 v = ((const float4*)in)[i];
    bf16x4 o;
    o[0] = (bf16)v.x; o[1] = (bf16)v.y; o[2] = (bf16)v.z; o[3] = (bf16)v.w;
    ((bf16x4*)out)[i] = o;
  }
}

// ---------------- x [B,C,HW] fp32 -> xb [B,HW,C] bf16 ----------------
__global__ __launch_bounds__(256)
void transpose_convert(const float* __restrict__ x, bf16* __restrict__ xb) {
  __shared__ float tile[64][65];
  const int tx = threadIdx.x & 15;
  const int ty = threadIdx.x >> 4;
  const int b   = blockIdx.z;
  const int c0  = blockIdx.y * 64;
  const int hw0 = blockIdx.x * 64;
  const float* xp = x + ((size_t)b * 2048 + c0) * 1024 + hw0;
#pragma unroll
  for (int i = 0; i < 4; ++i) {
    const int c = i * 16 + ty;
    const float4 v = *(const float4*)(xp + (size_t)c * 1024 + tx * 4);
    tile[c][tx * 4 + 0] = v.x; tile[c][tx * 4 + 1] = v.y;
    tile[c][tx * 4 + 2] = v.z; tile[c][tx * 4 + 3] = v.w;
  }
  __syncthreads();
  bf16* op = xb + ((size_t)b * 1024 + hw0) * 2048 + c0;
#pragma unroll
  for (int i = 0; i < 4; ++i) {
    const int hw = i * 16 + ty;
    bf16x4 o;
    o[0] = (bf16)tile[tx * 4 + 0][hw];
    o[1] = (bf16)tile[tx * 4 + 1][hw];
    o[2] = (bf16)tile[tx * 4 + 2][hw];
    o[3] = (bf16)tile[tx * 4 + 3][hw];
    *(bf16x4*)(op + (size_t)hw * 2048 + tx * 4) = o;
  }
}

// ---------------- GEMM1: hb[M,1024] = xb[M,2048] . w1b^T, fused BN-stats partials ----------------
// 256x256 tile, BK=32, ring-4 LDS double... quadruple-buffer with COUNTED vmcnt (never 0 in loop).
// Per phase t: STAGE(t+3) -> slot[(t+3)&3] (overwrites slot of t-1, whose reads finished before
// the t-1 barrier); ds_read frags of tile t (confirmed landed by vmcnt(8)+barrier at t-1);
// 32 MFMA under setprio(1); vmcnt(8) retires tile t+1's 4 loads; raw s_barrier.
// LDS layout per slot: 128 super-rows x 64 bf16 (2 m-rows per super-row), chunk XOR swizzle
// (phys chunk = logical ^ (srow&7)), inverse-swizzle applied to the global source address.
__global__ __launch_bounds__(512, 2)
void gemm1(const bf16* __restrict__ A, const bf16* __restrict__ Bt,
           bf16* __restrict__ Cb, float* __restrict__ S1, float* __restrict__ S2) {
  __shared__ __align__(16) bf16 As[4 * 8192];   // 4 slots x 16 KiB
  __shared__ __align__(16) bf16 Bs[4 * 8192];
  const int K = 2048, N = 1024, NT = 64;
  const int tid  = threadIdx.x;
  const int wave = tid >> 6;
  const int lane = tid & 63;
  const int id = blockIdx.x;                 // 512 blocks, 512 % 8 == 0 -> bijective XCD swizzle
  const int bn = (id >> 3) & 3;              // within an XCD: bn fastest -> 4 blocks sharing an
  const int bm = (id & 7) * 16 + (id >> 5);  // A-panel are temporally adjacent on the SAME XCD
  const int wr = wave >> 2, wc = wave & 3;   // 2 x 4 wave grid, wave tile 128 x 64

  // ---- staging lane constants (inverse-swizzled global source, linear LDS dest) ----
  const int srl = lane >> 3;                 // super-row within this wave's 8
  const int sc  = (lane & 7) ^ srl;          // swizzled source chunk 0..7
  const int sgr = 2 * (wave * 8 + srl) + (sc >> 2);  // row within 256-row panel (round 0)
  const int sk  = (sc & 3) * 8;              // k element offset 0..24
  const bf16* Ag = A  + (size_t)(bm * 256 + sgr) * K + sk;
  const bf16* Bg = Bt + (size_t)(bn * 256 + sgr) * K + sk;
  const int ldst = wave * 1024 + lane * 16;  // byte offset within a round; round 1 adds 8192

  // ---- ds-read lane constants ----
  const int mrow = lane & 15;
  const int kq   = lane >> 4;
  const int srA  = mrow >> 1;                                  // 0..7
  const int pch  = (((mrow & 1) << 2) + kq) ^ srA;             // phys chunk
  const int aoff = (wr * 64 + srA) * 128 + pch * 16;           // + r*1024
  const int boff = (wc * 32 + srA) * 128 + pch * 16;           // + c*1024

  f32x4 acc[8][4];
#pragma unroll
  for (int r = 0; r < 8; ++r)
#pragma unroll
    for (int c = 0; c < 4; ++c) acc[r][c] = (f32x4){0.f, 0.f, 0.f, 0.f};

#define STAGE(tt) do {                                                        \
    const int s_ = (tt) & 3;                                                  \
    const bf16* a_ = Ag + (tt) * 32;                                          \
    const bf16* b_ = Bg + (tt) * 32;                                          \
    char* da_ = (char*)As + s_ * 16384 + ldst;                                \
    char* db_ = (char*)Bs + s_ * 16384 + ldst;                                \
    async_copy16(da_,        a_);                                             \
    async_copy16(da_ + 8192, a_ + (size_t)128 * K);                           \
    async_copy16(db_,        b_);                                             \
    async_copy16(db_ + 8192, b_ + (size_t)128 * K);                           \
  } while (0)

#define COMPUTE(tt) do {                                                      \
    const char* Ab_ = (const char*)As + ((tt) & 3) * 16384 + aoff;            \
    const char* Bb_ = (const char*)Bs + ((tt) & 3) * 16384 + boff;            \
    bf16x8 af[8], bfr[4];                                                     \
    _Pragma("unroll")                                                         \
    for (int c = 0; c < 4; ++c) bfr[c] = *(const bf16x8*)(Bb_ + c * 1024);    \
    _Pragma("unroll")                                                         \
    for (int r = 0; r < 8; ++r) af[r] = *(const bf16x8*)(Ab_ + r * 1024);     \
    __builtin_amdgcn_s_setprio(1);                                            \
    _Pragma("unroll")                                                         \
    for (int r = 0; r < 8; ++r)                                               \
      _Pragma("unroll")                                                       \
      for (int c = 0; c < 4; ++c)                                             \
        acc[r][c] = __builtin_amdgcn_mfma_f32_16x16x32_bf16(af[r], bfr[c],    \
                                                            acc[r][c], 0, 0, 0); \
    __builtin_amdgcn_s_setprio(0);                                            \
  } while (0)

  // prologue: 3 tiles in flight, confirm tile 0
  STAGE(0); STAGE(1); STAGE(2);
  asm volatile("s_waitcnt vmcnt(8)" ::: "memory");
  __builtin_amdgcn_s_barrier();
  __builtin_amdgcn_sched_barrier(0);

  for (int t = 0; t < NT - 3; ++t) {
    STAGE(t + 3);
    COMPUTE(t);
    asm volatile("s_waitcnt vmcnt(8)" ::: "memory");  // retire tile t+1's 4 loads; t+2,t+3 in flight
    __builtin_amdgcn_s_barrier();
    __builtin_amdgcn_sched_barrier(0);
  }
  COMPUTE(NT - 3);
  asm volatile("s_waitcnt vmcnt(4)" ::: "memory");
  __builtin_amdgcn_s_barrier();
  __builtin_amdgcn_sched_barrier(0);
  COMPUTE(NT - 2);
  asm volatile("s_waitcnt vmcnt(0)" ::: "memory");
  __builtin_amdgcn_s_barrier();
  __builtin_amdgcn_sched_barrier(0);
  COMPUTE(NT - 1);
  __builtin_amdgcn_s_barrier();   // all LDS reads done before epilogue repurposes As

#undef STAGE
#undef COMPUTE

  // ---- C-write: col = lane&15 (= mrow), row = kq*4 + i ----
#pragma unroll
  for (int r = 0; r < 8; ++r)
#pragma unroll
    for (int c = 0; c < 4; ++c)
#pragma unroll
      for (int i = 0; i < 4; ++i) {
        const int gm = bm * 256 + wr * 128 + r * 16 + kq * 4 + i;
        const int gn = bn * 256 + wc * 64 + c * 16 + mrow;
        Cb[(size_t)gm * N + gn] = (bf16)acc[r][c][i];
      }

  // ---- fused BN-stats partials over this block's 256 rows ----
  float* S1s = (float*)As;        // [2][256]
  float* S2s = S1s + 512;         // [2][256]
#pragma unroll
  for (int c = 0; c < 4; ++c) {
    float a = 0.f, b = 0.f;
#pragma unroll
    for (int r = 0; r < 8; ++r)
#pragma unroll
      for (int i = 0; i < 4; ++i) { const float v = acc[r][c][i]; a += v; b += v * v; }
#pragma unroll
    for (int msk = 16; msk < 64; msk <<= 1) { a += __shfl_xor(a, msk, 64); b += __shfl_xor(b, msk, 64); }
    if (lane < 16) {
      S1s[wr * 256 + wc * 64 + c * 16 + lane] = a;
      S2s[wr * 256 + wc * 64 + c * 16 + lane] = b;
    }
  }
  __syncthreads();
  if (tid < 256) {
    atomicAdd(&S1[bn * 256 + tid], S1s[tid] + S1s[256 + tid]);
    atomicAdd(&S2[bn * 256 + tid], S2s[tid] + S2s[256 + tid]);
  }
}

// ---------------- BN finalize: S1/S2 -> scale/shift ----------------
__global__ __launch_bounds__(256)
void bn_finalize(const float* __restrict__ S1, const float* __restrict__ S2,
                 const float* __restrict__ gamma, const float* __restrict__ beta,
                 float* __restrict__ scale, float* __restrict__ shift) {
  const int d = blockIdx.x * 256 + threadIdx.x;  // 1024 channels
  const float inv_n = 1.0f / 32768.0f;
  const float mean = S1[d] * inv_n;
  const float var  = S2[d] * inv_n - mean * mean;
  const float rstd = rsqrtf(var + 1e-5f);
  const float sc = gamma[d] * rstd;
  scale[d] = sc;
  shift[d] = beta[d] - mean * sc;
}

// ---------------- GEMM2 fused: f = relu(hb*scale+shift) . w2b^T, row-L2-normalize, g-accumulate --------
__global__ __launch_bounds__(512, 4)
void gemm2f(const bf16* __restrict__ A, const bf16* __restrict__ Bt,
            const float* __restrict__ scale, const float* __restrict__ shift,
            float* __restrict__ g) {
  __shared__ __align__(16) bf16 As[128 * 64];
  __shared__ __align__(16) bf16 Bs[256 * 64];
  const int K = 1024;
  const int tid  = threadIdx.x;
  const int wave = tid >> 6;
  const int lane = tid & 63;
  const int bm = blockIdx.x;                 // 256 blocks, full 256-wide rows
  const int wr = wave >> 2, wc = wave & 3;   // 2 x 4 wave grid, wave tile 64x64
  const int srow = lane >> 3;
  const int scol = (lane & 7) ^ srow;

  f32x4 acc[4][4];
#pragma unroll
  for (int r = 0; r < 4; ++r)
#pragma unroll
    for (int c = 0; c < 4; ++c) acc[r][c] = (f32x4){0.f, 0.f, 0.f, 0.f};

  const bf16* Ag = A + (size_t)(bm * 128) * K;

  const int mrow = lane & 15;
  const int kq = lane >> 4;
  const int sw = mrow & 7;
  const bf16* Asw = As + (wr * 64) * 64;
  const bf16* Bsw = Bs + (wc * 64) * 64;

  for (int k0 = 0; k0 < K; k0 += 64) {
#pragma unroll
    for (int j = 0; j < 2; ++j) {
      const int row = wave * 16 + j * 8;
      async_copy16((void*)(As + row * 64),
                   (const void*)(Ag + (size_t)(row + srow) * K + k0 + scol * 8));
    }
#pragma unroll
    for (int j = 0; j < 4; ++j) {
      const int row = wave * 32 + j * 8;
      async_copy16((void*)(Bs + row * 64),
                   (const void*)(Bt + (size_t)(row + srow) * K + k0 + scol * 8));
    }
    __syncthreads();
#pragma unroll
    for (int kk = 0; kk < 2; ++kk) {
      const int lc = kk * 4 + kq;
      const int kbase = k0 + lc * 8;
      const float4 sc0 = *(const float4*)(scale + kbase);
      const float4 sc1 = *(const float4*)(scale + kbase + 4);
      const float4 sh0 = *(const float4*)(shift + kbase);
      const float4 sh1 = *(const float4*)(shift + kbase + 4);
      const float scv[8] = {sc0.x, sc0.y, sc0.z, sc0.w, sc1.x, sc1.y, sc1.z, sc1.w};
      const float shv[8] = {sh0.x, sh0.y, sh0.z, sh0.w, sh1.x, sh1.y, sh1.z, sh1.w};
      bf16x8 af[4], bfr[4];
#pragma unroll
      for (int r = 0; r < 4; ++r) {
        bf16x8 a = *(const bf16x8*)(Asw + (r * 16 + mrow) * 64 + ((lc ^ sw) * 8));
#pragma unroll
        for (int j = 0; j < 8; ++j)
          a[j] = (bf16)fmaxf(0.f, fmaf((float)a[j], scv[j], shv[j]));
        af[r] = a;
      }
#pragma unroll
      for (int c = 0; c < 4; ++c)
        bfr[c] = *(const bf16x8*)(Bsw + (c * 16 + mrow) * 64 + ((lc ^ sw) * 8));
#pragma unroll
      for (int r = 0; r < 4; ++r)
#pragma unroll
        for (int c = 0; c < 4; ++c)
          acc[r][c] = __builtin_amdgcn_mfma_f32_16x16x32_bf16(af[r], bfr[c], acc[r][c], 0, 0, 0);
    }
    __syncthreads();
  }

  // ---- epilogue: row L2 norms + g accumulation (f never hits HBM) ----
  float* ss4   = (float*)As;      // [4 wc][128 rows]
  float* inv_s = ss4 + 512;       // [128]
  const int q = lane >> 4;
#pragma unroll
  for (int r = 0; r < 4; ++r) {
    float ssv[4];
#pragma unroll
    for (int i = 0; i < 4; ++i) {
      float s = 0.f;
#pragma unroll
      for (int c = 0; c < 4; ++c) { const float v = acc[r][c][i]; s += v * v; }
#pragma unroll
      for (int msk = 1; msk < 16; msk <<= 1) s += __shfl_xor(s, msk, 64);
      ssv[i] = s;
    }
    if ((lane & 15) == 0)
#pragma unroll
      for (int i = 0; i < 4; ++i)
        ss4[wc * 128 + wr * 64 + r * 16 + q * 4 + i] = ssv[i];
  }
  __syncthreads();
  if (tid < 128) {
    const float rs = ss4[tid] + ss4[128 + tid] + ss4[256 + tid] + ss4[384 + tid];
    inv_s[tid] = 1.0f / fmaxf(sqrtf(rs), 1e-12f);
  }
  __syncthreads();
  const int b = bm >> 3;
  const int ccol = lane & 15;
#pragma unroll
  for (int c = 0; c < 4; ++c) {
    float gl = 0.f;
#pragma unroll
    for (int r = 0; r < 4; ++r)
#pragma unroll
      for (int i = 0; i < 4; ++i)
        gl += acc[r][c][i] * inv_s[wr * 64 + r * 16 + q * 4 + i];
#pragma unroll
    for (int msk = 16; msk < 64; msk <<= 1) gl += __shfl_xor(gl, msk, 64);
    if ((lane & 48) == 0)
      atomicAdd(&g[b * 256 + wc * 64 + c * 16 + ccol], gl);
  }
}

// ---------------- normalize prototypes + sim = g . p_norm^T ----------------
__global__ __launch_bounds__(256)
void sim_kernel(const float* __restrict__ g, const float* __restrict__ protos,
                float* __restrict__ out) {
  const int wave = threadIdx.x >> 6, lane = threadIdx.x & 63;
  const int n = blockIdx.x * 4 + wave;  // 1000 prototypes, grid 250
  const float4 p = *(const float4*)(protos + (size_t)n * 256 + lane * 4);
  float ss = p.x * p.x + p.y * p.y + p.z * p.z + p.w * p.w;
#pragma unroll
  for (int msk = 1; msk < 64; msk <<= 1) ss += __shfl_xor(ss, msk, 64);
  const float inv = 1.0f / fmaxf(sqrtf(ss), 1e-12f);
  const float px = p.x * inv, py = p.y * inv, pz = p.z * inv, pw = p.w * inv;
  for (int b = 0; b < 32; ++b) {
    const float4 gv = *(const float4*)(g + b * 256 + lane * 4);
    float d = px * gv.x + py * gv.y + pz * gv.z + pw * gv.w;
#pragma unroll
    for (int msk = 1; msk < 64; msk <<= 1) d += __shfl_xor(d, msk, 64);
    if (lane == 0) out[b * 1000 + n] = d;
  }
}

extern "C" void kernel_launch(void* const* d_in, const int* in_sizes, int n_in,
                              void* d_out, int out_size, void* d_ws, size_t ws_size,
                              hipStream_t stream) {
  const float* x      = (const float*)d_in[0];  // [32,2048,32,32]
  const float* w1     = (const float*)d_in[1];  // [1024,2048]
  const float* gamma  = (const float*)d_in[2];  // [1024]
  const float* beta   = (const float*)d_in[3];  // [1024]
  const float* w2     = (const float*)d_in[4];  // [256,1024]
  const float* protos = (const float*)d_in[5];  // [1000,256]
  float* out = (float*)d_out;                   // [32,1000]

  char* ws = (char*)d_ws;
  bf16*  xb    = (bf16*)(ws);
  bf16*  hb    = (bf16*)(ws + (size_t)134217728);
  bf16*  w1b   = (bf16*)(ws + (size_t)201326592);
  bf16*  w2b   = (bf16*)(ws + (size_t)205520896);
  float* S1    = (float*)(ws + (size_t)206045184);
  float* S2    = (float*)(ws + (size_t)206049280);
  float* g     = (float*)(ws + (size_t)206053376);
  float* scale = (float*)(ws + (size_t)206086144);
  float* shift = (float*)(ws + (size_t)206090240);

  hipMemsetAsync(S1, 0, 40960, stream);  // S1 + S2 + g contiguous

  f2bf_kernel<<<2048, 256, 0, stream>>>(w1, w1b, 524288);
  f2bf_kernel<<<256, 256, 0, stream>>>(w2, w2b, 65536);
  transpose_convert<<<dim3(16, 32, 32), 256, 0, stream>>>(x, xb);
  gemm1<<<512, 512, 0, stream>>>(xb, w1b, hb, S1, S2);
  bn_finalize<<<4, 256, 0, stream>>>(S1, S2, gamma, beta, scale, shift);
  gemm2f<<<256, 512, 0, stream>>>(hb, w2b, scale, shift, g);
  sim_kernel<<<250, 256, 0, stream>>>(g, protos, out);
}

// Round 3
// 644.202 us; speedup vs baseline: 1.0070x; 1.0070x over previous
//
#include <hip/hip_runtime.h>

typedef __bf16 bf16;
typedef __bf16 bf16x4 __attribute__((ext_vector_type(4)));
typedef __bf16 bf16x8 __attribute__((ext_vector_type(8)));
typedef float  f32x4  __attribute__((ext_vector_type(4)));

// async global->LDS, 16B per lane; LDS dest is wave-uniform base + lane*16
__device__ inline void async_copy16(void* lds, const void* g) {
  __builtin_amdgcn_global_load_lds((const __attribute__((address_space(1))) void*)g,
                                   (__attribute__((address_space(3))) void*)lds,
                                   16, 0, 0);
}

// ---------------- fp32 -> bf16 convert (weights) ----------------
__global__ __launch_bounds__(256)
void f2bf_kernel(const float* __restrict__ in, bf16* __restrict__ out, int n4) {
  int i = blockIdx.x * 256 + threadIdx.x;
  if (i < n4) {
    float4 v = ((const float4*)in)[i];
    bf16x4 o;
    o[0] = (bf16)v.x; o[1] = (bf16)v.y; o[2] = (bf16)v.z; o[3] = (bf16)v.w;
    ((bf16x4*)out)[i] = o;
  }
}

// ---------------- x [B,C,HW] fp32 -> xb [B,HW,C] bf16 ----------------
__global__ __launch_bounds__(256)
void transpose_convert(const float* __restrict__ x, bf16* __restrict__ xb) {
  __shared__ float tile[64][65];
  const int tx = threadIdx.x & 15;
  const int ty = threadIdx.x >> 4;
  const int b   = blockIdx.z;
  const int c0  = blockIdx.y * 64;
  const int hw0 = blockIdx.x * 64;
  const float* xp = x + ((size_t)b * 2048 + c0) * 1024 + hw0;
#pragma unroll
  for (int i = 0; i < 4; ++i) {
    const int c = i * 16 + ty;
    const float4 v = *(const float4*)(xp + (size_t)c * 1024 + tx * 4);
    tile[c][tx * 4 + 0] = v.x; tile[c][tx * 4 + 1] = v.y;
    tile[c][tx * 4 + 2] = v.z; tile[c][tx * 4 + 3] = v.w;
  }
  __syncthreads();
  bf16* op = xb + ((size_t)b * 1024 + hw0) * 2048 + c0;
#pragma unroll
  for (int i = 0; i < 4; ++i) {
    const int hw = i * 16 + ty;
    bf16x4 o;
    o[0] = (bf16)tile[tx * 4 + 0][hw];
    o[1] = (bf16)tile[tx * 4 + 1][hw];
    o[2] = (bf16)tile[tx * 4 + 2][hw];
    o[3] = (bf16)tile[tx * 4 + 3][hw];
    *(bf16x4*)(op + (size_t)hw * 2048 + tx * 4) = o;
  }
}

// ---------------- GEMM1: hb[M,1024] = xb[M,2048] . w1b^T, fused BN-stats partials ----------------
// m201-style quadrant-phase schedule. BM=256, BN=128, BK=64, 8 waves (4M x 2N),
// 3-ring LDS (slot = 48 KiB: A 256x64 + B 128x64), prefetch distance 2 K-tiles.
// Per K-tile: 2 phases. Phase 1: 12 ds_read_b128 (B all c/kk + A r0-1) || 3 stage loads
//   -> barrier -> lgkmcnt(0)+sched_barrier -> setprio(1) 16 MFMA setprio(0) -> barrier.
// Phase 2: 4 ds_read (A r2-3) || 3 stage loads -> barrier -> lgkm(0) -> 16 MFMA ->
//   vmcnt(6) (retires tile t+1's 6 loads; t+2's 6 stay in flight) -> barrier.
// LDS per m-row = 64 bf16 = 8 chunks of 16 B; phys chunk = logical ^ (row&7)
// (inverse swizzle on global source, swizzle on ds_read) - verified algebra from r0/r1.
__global__ __launch_bounds__(512, 2)
void gemm1(const bf16* __restrict__ A, const bf16* __restrict__ Bt,
           bf16* __restrict__ Cb, float* __restrict__ S1, float* __restrict__ S2) {
  __shared__ __align__(16) bf16 As[3 * 16384];   // 3 slots x 32 KiB (256 rows x 64)
  __shared__ __align__(16) bf16 Bs[3 * 8192];    // 3 slots x 16 KiB (128 rows x 64)
  const int K = 2048, N = 1024, NT = 32;
  const int tid  = threadIdx.x;
  const int wave = tid >> 6;
  const int lane = tid & 63;
  const int id = blockIdx.x;                 // 1024 blocks, 1024 % 8 == 0
  const int q  = id >> 3;                    // XCD-bijective: xcd = id&7
  const int bn = q & 7;                      // bn fastest within an XCD -> A-panel reuse in L2
  const int bm = (id & 7) * 16 + (q >> 3);   // 0..127
  const int wr = wave >> 1, wc = wave & 1;   // 4 x 2 wave grid; wave tile 64m x 64n

  // ---- staging lane constants (inverse-swizzled global source, linear LDS dest) ----
  const int srl = lane >> 3;                 // 0..7
  const int sch = (lane & 7) ^ srl;          // logical chunk this lane stages
  const int srow = wave * 8 + srl;           // 0..63; round j adds j*64
  const bf16* Ag = A  + (size_t)(bm * 256 + srow) * K + sch * 8;
  const bf16* Bg = Bt + (size_t)(bn * 128 + srow) * K + sch * 8;
  const int ldst = wave * 1024 + lane * 16;  // byte offset within an 8 KiB round

  // ---- ds-read lane constants ----
  const int mrow = lane & 15;
  const int kq   = lane >> 4;                // 0..3
  const int sw   = mrow & 7;
  const int aoff = (wr * 64 + mrow) * 128;   // + r*2048 + chunk*16
  const int boff = (wc * 64 + mrow) * 128;   // + c*2048 + chunk*16

  f32x4 acc[4][4];
#pragma unroll
  for (int r = 0; r < 4; ++r)
#pragma unroll
    for (int c = 0; c < 4; ++c) acc[r][c] = (f32x4){0.f, 0.f, 0.f, 0.f};

#define STA3(slot, tt) do {                                                   \
    char* da_ = (char*)As + (slot) * 32768 + ldst;                            \
    const bf16* a_ = Ag + (size_t)(tt) * 64;                                  \
    async_copy16(da_,         a_);                                            \
    async_copy16(da_ + 8192,  a_ + (size_t)64 * K);                           \
    async_copy16(da_ + 16384, a_ + (size_t)128 * K);                          \
  } while (0)
#define STB3(slot, tt) do {                                                   \
    char* da_ = (char*)As + (slot) * 32768 + ldst;                            \
    char* db_ = (char*)Bs + (slot) * 16384 + ldst;                            \
    const bf16* a_ = Ag + (size_t)(tt) * 64;                                  \
    const bf16* b_ = Bg + (size_t)(tt) * 64;                                  \
    async_copy16(da_ + 24576, a_ + (size_t)192 * K);                          \
    async_copy16(db_,         b_);                                            \
    async_copy16(db_ + 8192,  b_ + (size_t)64 * K);                           \
  } while (0)

  // prologue: tiles 0,1 staged (12 loads); vmcnt(6) -> tile 0 landed
  STA3(0, 0); STB3(0, 0);
  STA3(1, 1); STB3(1, 1);
  asm volatile("s_waitcnt vmcnt(6)" ::: "memory");
  __builtin_amdgcn_s_barrier();

  int srd = 0;   // slot of tile t
  int sst = 2;   // slot of tile t+2
  for (int t = 0; t < NT; ++t) {
    const char* Ab = (const char*)As + srd * 32768 + aoff;
    const char* Bb = (const char*)Bs + srd * 16384 + boff;
    const bool st = (t + 2 < NT);
    bf16x8 bfr[4][2], af[2][2];
    // -------- phase 1: B-frags (8) + A r0-1 (4) || stage A rounds 0-2 --------
#pragma unroll
    for (int c = 0; c < 4; ++c)
#pragma unroll
      for (int kk = 0; kk < 2; ++kk)
        bfr[c][kk] = *(const bf16x8*)(Bb + c * 2048 + ((kk * 4 + kq) ^ sw) * 16);
#pragma unroll
    for (int r = 0; r < 2; ++r)
#pragma unroll
      for (int kk = 0; kk < 2; ++kk)
        af[r][kk] = *(const bf16x8*)(Ab + r * 2048 + ((kk * 4 + kq) ^ sw) * 16);
    if (st) STA3(sst, t + 2);
    __builtin_amdgcn_s_barrier();
    asm volatile("s_waitcnt lgkmcnt(0)" ::: "memory");
    __builtin_amdgcn_sched_barrier(0);
    __builtin_amdgcn_s_setprio(1);
#pragma unroll
    for (int r = 0; r < 2; ++r)
#pragma unroll
      for (int c = 0; c < 4; ++c)
#pragma unroll
        for (int kk = 0; kk < 2; ++kk)
          acc[r][c] = __builtin_amdgcn_mfma_f32_16x16x32_bf16(af[r][kk], bfr[c][kk], acc[r][c], 0, 0, 0);
    __builtin_amdgcn_s_setprio(0);
    __builtin_amdgcn_s_barrier();
    // -------- phase 2: A r2-3 (4) || stage A round 3 + B rounds 0-1 --------
    bf16x8 af2[2][2];
#pragma unroll
    for (int r = 0; r < 2; ++r)
#pragma unroll
      for (int kk = 0; kk < 2; ++kk)
        af2[r][kk] = *(const bf16x8*)(Ab + (r + 2) * 2048 + ((kk * 4 + kq) ^ sw) * 16);
    if (st) STB3(sst, t + 2);
    __builtin_amdgcn_s_barrier();
    asm volatile("s_waitcnt lgkmcnt(0)" ::: "memory");
    __builtin_amdgcn_sched_barrier(0);
    __builtin_amdgcn_s_setprio(1);
#pragma unroll
    for (int r = 0; r < 2; ++r)
#pragma unroll
      for (int c = 0; c < 4; ++c)
#pragma unroll
        for (int kk = 0; kk < 2; ++kk)
          acc[r + 2][c] = __builtin_amdgcn_mfma_f32_16x16x32_bf16(af2[r][kk], bfr[c][kk], acc[r + 2][c], 0, 0, 0);
    __builtin_amdgcn_s_setprio(0);
    if (st) { asm volatile("s_waitcnt vmcnt(6)" ::: "memory"); }       // t+1 landed
    else if (t + 1 < NT) { asm volatile("s_waitcnt vmcnt(0)" ::: "memory"); }
    __builtin_amdgcn_s_barrier();
    srd = (srd == 2) ? 0 : srd + 1;
    sst = (sst == 2) ? 0 : sst + 1;
  }
#undef STA3
#undef STB3

  // ---- C-write: col = lane&15, row = (lane>>4)*4 + i ----
#pragma unroll
  for (int r = 0; r < 4; ++r)
#pragma unroll
    for (int c = 0; c < 4; ++c)
#pragma unroll
      for (int i = 0; i < 4; ++i) {
        const int gm = bm * 256 + wr * 64 + r * 16 + kq * 4 + i;
        const int gn = bn * 128 + wc * 64 + c * 16 + mrow;
        Cb[(size_t)gm * N + gn] = (bf16)acc[r][c][i];
      }

  // ---- fused BN-stats partials over this block's 256 rows, 128 cols ----
  float* S1s = (float*)As;        // [4 wr][128]
  float* S2s = S1s + 512;         // [4 wr][128]
#pragma unroll
  for (int c = 0; c < 4; ++c) {
    float a = 0.f, b = 0.f;
#pragma unroll
    for (int r = 0; r < 4; ++r)
#pragma unroll
      for (int i = 0; i < 4; ++i) { const float v = acc[r][c][i]; a += v; b += v * v; }
#pragma unroll
    for (int msk = 16; msk < 64; msk <<= 1) { a += __shfl_xor(a, msk, 64); b += __shfl_xor(b, msk, 64); }
    if (lane < 16) {
      S1s[wr * 128 + wc * 64 + c * 16 + lane] = a;
      S2s[wr * 128 + wc * 64 + c * 16 + lane] = b;
    }
  }
  __syncthreads();
  if (tid < 128) {
    const float a = S1s[tid] + S1s[128 + tid] + S1s[256 + tid] + S1s[384 + tid];
    const float b = S2s[tid] + S2s[128 + tid] + S2s[256 + tid] + S2s[384 + tid];
    atomicAdd(&S1[bn * 128 + tid], a);
    atomicAdd(&S2[bn * 128 + tid], b);
  }
}

// ---------------- BN finalize: S1/S2 -> scale/shift ----------------
__global__ __launch_bounds__(256)
void bn_finalize(const float* __restrict__ S1, const float* __restrict__ S2,
                 const float* __restrict__ gamma, const float* __restrict__ beta,
                 float* __restrict__ scale, float* __restrict__ shift) {
  const int d = blockIdx.x * 256 + threadIdx.x;  // 1024 channels
  const float inv_n = 1.0f / 32768.0f;
  const float mean = S1[d] * inv_n;
  const float var  = S2[d] * inv_n - mean * mean;
  const float rstd = rsqrtf(var + 1e-5f);
  const float sc = gamma[d] * rstd;
  scale[d] = sc;
  shift[d] = beta[d] - mean * sc;
}

// ---------------- GEMM2 fused: f = relu(hb*scale+shift) . w2b^T, row-L2-normalize, g-accumulate --------
__global__ __launch_bounds__(512, 4)
void gemm2f(const bf16* __restrict__ A, const bf16* __restrict__ Bt,
            const float* __restrict__ scale, const float* __restrict__ shift,
            float* __restrict__ g) {
  __shared__ __align__(16) bf16 As[128 * 64];
  __shared__ __align__(16) bf16 Bs[256 * 64];
  const int K = 1024;
  const int tid  = threadIdx.x;
  const int wave = tid >> 6;
  const int lane = tid & 63;
  const int bm = blockIdx.x;                 // 256 blocks, full 256-wide rows
  const int wr = wave >> 2, wc = wave & 3;   // 2 x 4 wave grid, wave tile 64x64
  const int srow = lane >> 3;
  const int scol = (lane & 7) ^ srow;

  f32x4 acc[4][4];
#pragma unroll
  for (int r = 0; r < 4; ++r)
#pragma unroll
    for (int c = 0; c < 4; ++c) acc[r][c] = (f32x4){0.f, 0.f, 0.f, 0.f};

  const bf16* Ag = A + (size_t)(bm * 128) * K;

  const int mrow = lane & 15;
  const int kq = lane >> 4;
  const int sw = mrow & 7;
  const bf16* Asw = As + (wr * 64) * 64;
  const bf16* Bsw = Bs + (wc * 64) * 64;

  for (int k0 = 0; k0 < K; k0 += 64) {
#pragma unroll
    for (int j = 0; j < 2; ++j) {
      const int row = wave * 16 + j * 8;
      async_copy16((void*)(As + row * 64),
                   (const void*)(Ag + (size_t)(row + srow) * K + k0 + scol * 8));
    }
#pragma unroll
    for (int j = 0; j < 4; ++j) {
      const int row = wave * 32 + j * 8;
      async_copy16((void*)(Bs + row * 64),
                   (const void*)(Bt + (size_t)(row + srow) * K + k0 + scol * 8));
    }
    __syncthreads();
#pragma unroll
    for (int kk = 0; kk < 2; ++kk) {
      const int lc = kk * 4 + kq;
      const int kbase = k0 + lc * 8;
      const float4 sc0 = *(const float4*)(scale + kbase);
      const float4 sc1 = *(const float4*)(scale + kbase + 4);
      const float4 sh0 = *(const float4*)(shift + kbase);
      const float4 sh1 = *(const float4*)(shift + kbase + 4);
      const float scv[8] = {sc0.x, sc0.y, sc0.z, sc0.w, sc1.x, sc1.y, sc1.z, sc1.w};
      const float shv[8] = {sh0.x, sh0.y, sh0.z, sh0.w, sh1.x, sh1.y, sh1.z, sh1.w};
      bf16x8 af[4], bfr[4];
#pragma unroll
      for (int r = 0; r < 4; ++r) {
        bf16x8 a = *(const bf16x8*)(Asw + (r * 16 + mrow) * 64 + ((lc ^ sw) * 8));
#pragma unroll
        for (int j = 0; j < 8; ++j)
          a[j] = (bf16)fmaxf(0.f, fmaf((float)a[j], scv[j], shv[j]));
        af[r] = a;
      }
#pragma unroll
      for (int c = 0; c < 4; ++c)
        bfr[c] = *(const bf16x8*)(Bsw + (c * 16 + mrow) * 64 + ((lc ^ sw) * 8));
#pragma unroll
      for (int r = 0; r < 4; ++r)
#pragma unroll
        for (int c = 0; c < 4; ++c)
          acc[r][c] = __builtin_amdgcn_mfma_f32_16x16x32_bf16(af[r], bfr[c], acc[r][c], 0, 0, 0);
    }
    __syncthreads();
  }

  // ---- epilogue: row L2 norms + g accumulation (f never hits HBM) ----
  float* ss4   = (float*)As;      // [4 wc][128 rows]
  float* inv_s = ss4 + 512;       // [128]
  const int q = lane >> 4;
#pragma unroll
  for (int r = 0; r < 4; ++r) {
    float ssv[4];
#pragma unroll
    for (int i = 0; i < 4; ++i) {
      float s = 0.f;
#pragma unroll
      for (int c = 0; c < 4; ++c) { const float v = acc[r][c][i]; s += v * v; }
#pragma unroll
      for (int msk = 1; msk < 16; msk <<= 1) s += __shfl_xor(s, msk, 64);
      ssv[i] = s;
    }
    if ((lane & 15) == 0)
#pragma unroll
      for (int i = 0; i < 4; ++i)
        ss4[wc * 128 + wr * 64 + r * 16 + q * 4 + i] = ssv[i];
  }
  __syncthreads();
  if (tid < 128) {
    const float rs = ss4[tid] + ss4[128 + tid] + ss4[256 + tid] + ss4[384 + tid];
    inv_s[tid] = 1.0f / fmaxf(sqrtf(rs), 1e-12f);
  }
  __syncthreads();
  const int b = bm >> 3;
  const int ccol = lane & 15;
#pragma unroll
  for (int c = 0; c < 4; ++c) {
    float gl = 0.f;
#pragma unroll
    for (int r = 0; r < 4; ++r)
#pragma unroll
      for (int i = 0; i < 4; ++i)
        gl += acc[r][c][i] * inv_s[wr * 64 + r * 16 + q * 4 + i];
#pragma unroll
    for (int msk = 16; msk < 64; msk <<= 1) gl += __shfl_xor(gl, msk, 64);
    if ((lane & 48) == 0)
      atomicAdd(&g[b * 256 + wc * 64 + c * 16 + ccol], gl);
  }
}

// ---------------- normalize prototypes + sim = g . p_norm^T ----------------
__global__ __launch_bounds__(256)
void sim_kernel(const float* __restrict__ g, const float* __restrict__ protos,
                float* __restrict__ out) {
  const int wave = threadIdx.x >> 6, lane = threadIdx.x & 63;
  const int n = blockIdx.x * 4 + wave;  // 1000 prototypes, grid 250
  const float4 p = *(const float4*)(protos + (size_t)n * 256 + lane * 4);
  float ss = p.x * p.x + p.y * p.y + p.z * p.z + p.w * p.w;
#pragma unroll
  for (int msk = 1; msk < 64; msk <<= 1) ss += __shfl_xor(ss, msk, 64);
  const float inv = 1.0f / fmaxf(sqrtf(ss), 1e-12f);
  const float px = p.x * inv, py = p.y * inv, pz = p.z * inv, pw = p.w * inv;
  for (int b = 0; b < 32; ++b) {
    const float4 gv = *(const float4*)(g + b * 256 + lane * 4);
    float d = px * gv.x + py * gv.y + pz * gv.z + pw * gv.w;
#pragma unroll
    for (int msk = 1; msk < 64; msk <<= 1) d += __shfl_xor(d, msk, 64);
    if (lane == 0) out[b * 1000 + n] = d;
  }
}

extern "C" void kernel_launch(void* const* d_in, const int* in_sizes, int n_in,
                              void* d_out, int out_size, void* d_ws, size_t ws_size,
                              hipStream_t stream) {
  const float* x      = (const float*)d_in[0];  // [32,2048,32,32]
  const float* w1     = (const float*)d_in[1];  // [1024,2048]
  const float* gamma  = (const float*)d_in[2];  // [1024]
  const float* beta   = (const float*)d_in[3];  // [1024]
  const float* w2     = (const float*)d_in[4];  // [256,1024]
  const float* protos = (const float*)d_in[5];  // [1000,256]
  float* out = (float*)d_out;                   // [32,1000]

  char* ws = (char*)d_ws;
  bf16*  xb    = (bf16*)(ws);
  bf16*  hb    = (bf16*)(ws + (size_t)134217728);
  bf16*  w1b   = (bf16*)(ws + (size_t)201326592);
  bf16*  w2b   = (bf16*)(ws + (size_t)205520896);
  float* S1    = (float*)(ws + (size_t)206045184);
  float* S2    = (float*)(ws + (size_t)206049280);
  float* g     = (float*)(ws + (size_t)206053376);
  float* scale = (float*)(ws + (size_t)206086144);
  float* shift = (float*)(ws + (size_t)206090240);

  hipMemsetAsync(S1, 0, 40960, stream);  // S1 + S2 + g contiguous

  f2bf_kernel<<<2048, 256, 0, stream>>>(w1, w1b, 524288);
  f2bf_kernel<<<256, 256, 0, stream>>>(w2, w2b, 65536);
  transpose_convert<<<dim3(16, 32, 32), 256, 0, stream>>>(x, xb);
  gemm1<<<1024, 512, 0, stream>>>(xb, w1b, hb, S1, S2);
  bn_finalize<<<4, 256, 0, stream>>>(S1, S2, gamma, beta, scale, shift);
  gemm2f<<<256, 512, 0, stream>>>(hb, w2b, scale, shift, g);
  sim_kernel<<<250, 256, 0, stream>>>(g, protos, out);
}

// Round 4
// 609.717 us; speedup vs baseline: 1.0640x; 1.0566x over previous
//
#include <hip/hip_runtime.h>

typedef __bf16 bf16;
typedef __bf16 bf16x4 __attribute__((ext_vector_type(4)));
typedef __bf16 bf16x8 __attribute__((ext_vector_type(8)));
typedef float  f32x4  __attribute__((ext_vector_type(4)));

// async global->LDS, 16B per lane; LDS dest is wave-uniform base + lane*16
__device__ inline void async_copy16(void* lds, const void* g) {
  __builtin_amdgcn_global_load_lds((const __attribute__((address_space(1))) void*)g,
                                   (__attribute__((address_space(3))) void*)lds,
                                   16, 0, 0);
}

// ---------------- fp32 -> bf16 convert (weights) ----------------
__global__ __launch_bounds__(256)
void f2bf_kernel(const float* __restrict__ in, bf16* __restrict__ out, int n4) {
  int i = blockIdx.x * 256 + threadIdx.x;
  if (i < n4) {
    float4 v = ((const float4*)in)[i];
    bf16x4 o;
    o[0] = (bf16)v.x; o[1] = (bf16)v.y; o[2] = (bf16)v.z; o[3] = (bf16)v.w;
    ((bf16x4*)out)[i] = o;
  }
}

// ---------------- x [B,C,HW] fp32 -> xb [B,HW,C] bf16 ----------------
__global__ __launch_bounds__(256)
void transpose_convert(const float* __restrict__ x, bf16* __restrict__ xb) {
  __shared__ float tile[64][65];
  const int tx = threadIdx.x & 15;
  const int ty = threadIdx.x >> 4;
  const int b   = blockIdx.z;
  const int c0  = blockIdx.y * 64;
  const int hw0 = blockIdx.x * 64;
  const float* xp = x + ((size_t)b * 2048 + c0) * 1024 + hw0;
#pragma unroll
  for (int i = 0; i < 4; ++i) {
    const int c = i * 16 + ty;
    const float4 v = *(const float4*)(xp + (size_t)c * 1024 + tx * 4);
    tile[c][tx * 4 + 0] = v.x; tile[c][tx * 4 + 1] = v.y;
    tile[c][tx * 4 + 2] = v.z; tile[c][tx * 4 + 3] = v.w;
  }
  __syncthreads();
  bf16* op = xb + ((size_t)b * 1024 + hw0) * 2048 + c0;
#pragma unroll
  for (int i = 0; i < 4; ++i) {
    const int hw = i * 16 + ty;
    bf16x4 o;
    o[0] = (bf16)tile[tx * 4 + 0][hw];
    o[1] = (bf16)tile[tx * 4 + 1][hw];
    o[2] = (bf16)tile[tx * 4 + 2][hw];
    o[3] = (bf16)tile[tx * 4 + 3][hw];
    *(bf16x4*)(op + (size_t)hw * 2048 + tx * 4) = o;
  }
}

// ---------------- GEMM1: hb[M,1024] = xb[M,2048] . w1b^T, fused BN-stats partials ----------------
// 128x128 tile, BK=64, XOR-swizzled LDS (conflict-free), XCD-aware block mapping:
// xcd = id&7; within an XCD bn iterates fastest so the 8 blocks sharing an A-tile
// are temporally adjacent on the SAME XCD -> A fetched ~once from HBM.
__global__ __launch_bounds__(256, 4)
void gemm1(const bf16* __restrict__ A, const bf16* __restrict__ Bt,
           bf16* __restrict__ Cb, float* __restrict__ S1, float* __restrict__ S2) {
  __shared__ __align__(16) bf16 As[128 * 64];
  __shared__ __align__(16) bf16 Bs[128 * 64];
  const int K = 2048, N = 1024;
  const int tid  = threadIdx.x;
  const int wave = tid >> 6;
  const int lane = tid & 63;
  const int id = blockIdx.x;                 // 2048 blocks
  const int bm = (id & 7) * 32 + ((id >> 3) >> 3);
  const int bn = (id >> 3) & 7;
  const int wr = wave >> 1, wc = wave & 1;
  const int srow = lane >> 3;
  const int scol = (lane & 7) ^ srow;        // staged (swizzled) source chunk

  f32x4 acc[4][4];
#pragma unroll
  for (int r = 0; r < 4; ++r)
#pragma unroll
    for (int c = 0; c < 4; ++c) acc[r][c] = (f32x4){0.f, 0.f, 0.f, 0.f};

  const bf16* Ag = A + (size_t)(bm * 128) * K;
  const bf16* Bg = Bt + (size_t)(bn * 128) * K;

  const int mrow = lane & 15;
  const int kq = lane >> 4;
  const int sw = mrow & 7;
  const bf16* Asw = As + (wr * 64) * 64;
  const bf16* Bsw = Bs + (wc * 64) * 64;

  for (int k0 = 0; k0 < K; k0 += 64) {
#pragma unroll
    for (int j = 0; j < 4; ++j) {
      const int row = j * 32 + wave * 8;
      async_copy16((void*)(As + row * 64),
                   (const void*)(Ag + (size_t)(row + srow) * K + k0 + scol * 8));
      async_copy16((void*)(Bs + row * 64),
                   (const void*)(Bg + (size_t)(row + srow) * K + k0 + scol * 8));
    }
    __syncthreads();
#pragma unroll
    for (int kk = 0; kk < 2; ++kk) {
      bf16x8 af[4], bfr[4];
      const int lc = kk * 4 + kq;
#pragma unroll
      for (int r = 0; r < 4; ++r)
        af[r] = *(const bf16x8*)(Asw + (r * 16 + mrow) * 64 + ((lc ^ sw) * 8));
#pragma unroll
      for (int c = 0; c < 4; ++c)
        bfr[c] = *(const bf16x8*)(Bsw + (c * 16 + mrow) * 64 + ((lc ^ sw) * 8));
#pragma unroll
      for (int r = 0; r < 4; ++r)
#pragma unroll
        for (int c = 0; c < 4; ++c)
          acc[r][c] = __builtin_amdgcn_mfma_f32_16x16x32_bf16(af[r], bfr[c], acc[r][c], 0, 0, 0);
    }
    __syncthreads();
  }

  // C/D layout: col = lane&15, row = (lane>>4)*4 + reg
  const int crow = (lane >> 4) * 4;
  const int ccol = lane & 15;
#pragma unroll
  for (int r = 0; r < 4; ++r)
#pragma unroll
    for (int c = 0; c < 4; ++c)
#pragma unroll
      for (int i = 0; i < 4; ++i) {
        const int gm = bm * 128 + wr * 64 + r * 16 + crow + i;
        const int gn = bn * 128 + wc * 64 + c * 16 + ccol;
        Cb[(size_t)gm * N + gn] = (bf16)acc[r][c][i];
      }

  // Fused BN-stats partials: per-column sum/sumsq over this block's 128 rows.
  float s1[4], s2[4];
#pragma unroll
  for (int c = 0; c < 4; ++c) {
    float a = 0.f, b = 0.f;
#pragma unroll
    for (int r = 0; r < 4; ++r)
#pragma unroll
      for (int i = 0; i < 4; ++i) { const float v = acc[r][c][i]; a += v; b += v * v; }
    // reduce over row-quadrant lanes (same ccol, different lane>>4)
#pragma unroll
    for (int msk = 16; msk < 64; msk <<= 1) { a += __shfl_xor(a, msk, 64); b += __shfl_xor(b, msk, 64); }
    s1[c] = a; s2[c] = b;
  }
  float* S1s = (float*)As;        // [2][128]
  float* S2s = S1s + 256;         // [2][128]
  if ((lane & 15) == lane) {      // lanes 0..15 of each wave
#pragma unroll
    for (int c = 0; c < 4; ++c) {
      S1s[wr * 128 + wc * 64 + c * 16 + lane] = s1[c];
      S2s[wr * 128 + wc * 64 + c * 16 + lane] = s2[c];
    }
  }
  __syncthreads();
  if (tid < 128) {
    atomicAdd(&S1[bn * 128 + tid], S1s[tid] + S1s[128 + tid]);
    atomicAdd(&S2[bn * 128 + tid], S2s[tid] + S2s[128 + tid]);
  }
}

// ---------------- BN finalize: S1/S2 -> scale/shift ----------------
__global__ __launch_bounds__(256)
void bn_finalize(const float* __restrict__ S1, const float* __restrict__ S2,
                 const float* __restrict__ gamma, const float* __restrict__ beta,
                 float* __restrict__ scale, float* __restrict__ shift) {
  const int d = blockIdx.x * 256 + threadIdx.x;  // 1024 channels
  const float inv_n = 1.0f / 32768.0f;
  const float mean = S1[d] * inv_n;
  const float var  = S2[d] * inv_n - mean * mean;
  const float rstd = rsqrtf(var + 1e-5f);
  const float sc = gamma[d] * rstd;
  scale[d] = sc;
  shift[d] = beta[d] - mean * sc;
}

// ---------------- GEMM2 fused: f = relu(hb*scale+shift) . w2b^T, row-L2-normalize, g-accumulate --------
// 512 threads (8 waves, 2x4), tile 128m x 256n, BK=64. BN+ReLU applied on A-fragments.
// Epilogue: per-row ss (shfl+LDS), inv = 1/max(sqrt(ss),eps), g[b][n] += sum_m f*inv.
// launch_bounds (512,2): grid is 256 blocks on 256 CUs (1 block/CU regardless), so the
// only effect of the 2nd arg is the register cap -- (512,4)'s 128-reg cap risked spill.
__global__ __launch_bounds__(512, 2)
void gemm2f(const bf16* __restrict__ A, const bf16* __restrict__ Bt,
            const float* __restrict__ scale, const float* __restrict__ shift,
            float* __restrict__ g) {
  __shared__ __align__(16) bf16 As[128 * 64];
  __shared__ __align__(16) bf16 Bs[256 * 64];
  const int K = 1024;
  const int tid  = threadIdx.x;
  const int wave = tid >> 6;
  const int lane = tid & 63;
  const int bm = blockIdx.x;                 // 256 blocks, full 256-wide rows
  const int wr = wave >> 2, wc = wave & 3;   // 2 x 4 wave grid, wave tile 64x64
  const int srow = lane >> 3;
  const int scol = (lane & 7) ^ srow;

  f32x4 acc[4][4];
#pragma unroll
  for (int r = 0; r < 4; ++r)
#pragma unroll
    for (int c = 0; c < 4; ++c) acc[r][c] = (f32x4){0.f, 0.f, 0.f, 0.f};

  const bf16* Ag = A + (size_t)(bm * 128) * K;

  const int mrow = lane & 15;
  const int kq = lane >> 4;
  const int sw = mrow & 7;
  const bf16* Asw = As + (wr * 64) * 64;
  const bf16* Bsw = Bs + (wc * 64) * 64;

  for (int k0 = 0; k0 < K; k0 += 64) {
#pragma unroll
    for (int j = 0; j < 2; ++j) {
      const int row = wave * 16 + j * 8;
      async_copy16((void*)(As + row * 64),
                   (const void*)(Ag + (size_t)(row + srow) * K + k0 + scol * 8));
    }
#pragma unroll
    for (int j = 0; j < 4; ++j) {
      const int row = wave * 32 + j * 8;
      async_copy16((void*)(Bs + row * 64),
                   (const void*)(Bt + (size_t)(row + srow) * K + k0 + scol * 8));
    }
    __syncthreads();
#pragma unroll
    for (int kk = 0; kk < 2; ++kk) {
      const int lc = kk * 4 + kq;
      const int kbase = k0 + lc * 8;
      const float4 sc0 = *(const float4*)(scale + kbase);
      const float4 sc1 = *(const float4*)(scale + kbase + 4);
      const float4 sh0 = *(const float4*)(shift + kbase);
      const float4 sh1 = *(const float4*)(shift + kbase + 4);
      const float scv[8] = {sc0.x, sc0.y, sc0.z, sc0.w, sc1.x, sc1.y, sc1.z, sc1.w};
      const float shv[8] = {sh0.x, sh0.y, sh0.z, sh0.w, sh1.x, sh1.y, sh1.z, sh1.w};
      bf16x8 af[4], bfr[4];
#pragma unroll
      for (int r = 0; r < 4; ++r) {
        bf16x8 a = *(const bf16x8*)(Asw + (r * 16 + mrow) * 64 + ((lc ^ sw) * 8));
#pragma unroll
        for (int j = 0; j < 8; ++j)
          a[j] = (bf16)fmaxf(0.f, fmaf((float)a[j], scv[j], shv[j]));
        af[r] = a;
      }
#pragma unroll
      for (int c = 0; c < 4; ++c)
        bfr[c] = *(const bf16x8*)(Bsw + (c * 16 + mrow) * 64 + ((lc ^ sw) * 8));
#pragma unroll
      for (int r = 0; r < 4; ++r)
#pragma unroll
        for (int c = 0; c < 4; ++c)
          acc[r][c] = __builtin_amdgcn_mfma_f32_16x16x32_bf16(af[r], bfr[c], acc[r][c], 0, 0, 0);
    }
    __syncthreads();
  }

  // ---- epilogue: row L2 norms + g accumulation (f never hits HBM) ----
  float* ss4   = (float*)As;      // [4 wc][128 rows]
  float* inv_s = ss4 + 512;       // [128]
  const int q = lane >> 4;
  // (a) per-row sum of squares over this wave's 64 cols
#pragma unroll
  for (int r = 0; r < 4; ++r) {
    float ssv[4];
#pragma unroll
    for (int i = 0; i < 4; ++i) {
      float s = 0.f;
#pragma unroll
      for (int c = 0; c < 4; ++c) { const float v = acc[r][c][i]; s += v * v; }
#pragma unroll
      for (int msk = 1; msk < 16; msk <<= 1) s += __shfl_xor(s, msk, 64);
      ssv[i] = s;
    }
    if ((lane & 15) == 0)
#pragma unroll
      for (int i = 0; i < 4; ++i)
        ss4[wc * 128 + wr * 64 + r * 16 + q * 4 + i] = ssv[i];
  }
  __syncthreads();
  if (tid < 128) {
    const float rs = ss4[tid] + ss4[128 + tid] + ss4[256 + tid] + ss4[384 + tid];
    inv_s[tid] = 1.0f / fmaxf(sqrtf(rs), 1e-12f);
  }
  __syncthreads();
  // (b) g[b][col] += sum over rows of f*inv
  const int b = bm >> 3;
  const int ccol = lane & 15;
#pragma unroll
  for (int c = 0; c < 4; ++c) {
    float gl = 0.f;
#pragma unroll
    for (int r = 0; r < 4; ++r)
#pragma unroll
      for (int i = 0; i < 4; ++i)
        gl += acc[r][c][i] * inv_s[wr * 64 + r * 16 + q * 4 + i];
#pragma unroll
    for (int msk = 16; msk < 64; msk <<= 1) gl += __shfl_xor(gl, msk, 64);
    if ((lane & 48) == 0)
      atomicAdd(&g[b * 256 + wc * 64 + c * 16 + ccol], gl);
  }
}

// ---------------- normalize prototypes + sim = g . p_norm^T ----------------
__global__ __launch_bounds__(256)
void sim_kernel(const float* __restrict__ g, const float* __restrict__ protos,
                float* __restrict__ out) {
  const int wave = threadIdx.x >> 6, lane = threadIdx.x & 63;
  const int n = blockIdx.x * 4 + wave;  // 1000 prototypes, grid 250
  const float4 p = *(const float4*)(protos + (size_t)n * 256 + lane * 4);
  float ss = p.x * p.x + p.y * p.y + p.z * p.z + p.w * p.w;
#pragma unroll
  for (int msk = 1; msk < 64; msk <<= 1) ss += __shfl_xor(ss, msk, 64);
  const float inv = 1.0f / fmaxf(sqrtf(ss), 1e-12f);
  const float px = p.x * inv, py = p.y * inv, pz = p.z * inv, pw = p.w * inv;
  for (int b = 0; b < 32; ++b) {
    const float4 gv = *(const float4*)(g + b * 256 + lane * 4);
    float d = px * gv.x + py * gv.y + pz * gv.z + pw * gv.w;
#pragma unroll
    for (int msk = 1; msk < 64; msk <<= 1) d += __shfl_xor(d, msk, 64);
    if (lane == 0) out[b * 1000 + n] = d;
  }
}

extern "C" void kernel_launch(void* const* d_in, const int* in_sizes, int n_in,
                              void* d_out, int out_size, void* d_ws, size_t ws_size,
                              hipStream_t stream) {
  const float* x      = (const float*)d_in[0];  // [32,2048,32,32]
  const float* w1     = (const float*)d_in[1];  // [1024,2048]
  const float* gamma  = (const float*)d_in[2];  // [1024]
  const float* beta   = (const float*)d_in[3];  // [1024]
  const float* w2     = (const float*)d_in[4];  // [256,1024]
  const float* protos = (const float*)d_in[5];  // [1000,256]
  float* out = (float*)d_out;                   // [32,1000]

  char* ws = (char*)d_ws;
  // layout (bytes):
  //   0         : xb  [32768,2048] bf16  (128 MiB)
  //   128 MiB   : hb  [32768,1024] bf16  ( 64 MiB)
  //   192 MiB   : w1b (4 MiB), w2b (0.5 MiB)
  //   then      : S1(4K) S2(4K) g(32K) scale(4K) shift(4K)
  bf16*  xb    = (bf16*)(ws);
  bf16*  hb    = (bf16*)(ws + (size_t)134217728);
  bf16*  w1b   = (bf16*)(ws + (size_t)201326592);
  bf16*  w2b   = (bf16*)(ws + (size_t)205520896);
  float* S1    = (float*)(ws + (size_t)206045184);
  float* S2    = (float*)(ws + (size_t)206049280);
  float* g     = (float*)(ws + (size_t)206053376);
  float* scale = (float*)(ws + (size_t)206086144);
  float* shift = (float*)(ws + (size_t)206090240);

  hipMemsetAsync(S1, 0, 40960, stream);  // S1 + S2 + g contiguous

  f2bf_kernel<<<2048, 256, 0, stream>>>(w1, w1b, 524288);
  f2bf_kernel<<<256, 256, 0, stream>>>(w2, w2b, 65536);
  transpose_convert<<<dim3(16, 32, 32), 256, 0, stream>>>(x, xb);
  gemm1<<<2048, 256, 0, stream>>>(xb, w1b, hb, S1, S2);
  bn_finalize<<<4, 256, 0, stream>>>(S1, S2, gamma, beta, scale, shift);
  gemm2f<<<256, 512, 0, stream>>>(hb, w2b, scale, shift, g);
  sim_kernel<<<250, 256, 0, stream>>>(g, protos, out);
}

// Round 5
// 598.381 us; speedup vs baseline: 1.0841x; 1.0189x over previous
//
#include <hip/hip_runtime.h>

typedef __bf16 bf16;
typedef __bf16 bf16x4 __attribute__((ext_vector_type(4)));
typedef __bf16 bf16x8 __attribute__((ext_vector_type(8)));
typedef float  f32x4  __attribute__((ext_vector_type(4)));

// async global->LDS, 16B per lane; LDS dest is wave-uniform base + lane*16
__device__ inline void async_copy16(void* lds, const void* g) {
  __builtin_amdgcn_global_load_lds((const __attribute__((address_space(1))) void*)g,
                                   (__attribute__((address_space(3))) void*)lds,
                                   16, 0, 0);
}

// ---------------- fp32 -> bf16 convert (weights) ----------------
__global__ __launch_bounds__(256)
void f2bf_kernel(const float* __restrict__ in, bf16* __restrict__ out, int n4) {
  int i = blockIdx.x * 256 + threadIdx.x;
  if (i < n4) {
    float4 v = ((const float4*)in)[i];
    bf16x4 o;
    o[0] = (bf16)v.x; o[1] = (bf16)v.y; o[2] = (bf16)v.z; o[3] = (bf16)v.w;
    ((bf16x4*)out)[i] = o;
  }
}

// ---------------- x [B,C,HW] fp32 -> xb [B,HW,C] bf16 ----------------
__global__ __launch_bounds__(256)
void transpose_convert(const float* __restrict__ x, bf16* __restrict__ xb) {
  __shared__ float tile[64][65];
  const int tx = threadIdx.x & 15;
  const int ty = threadIdx.x >> 4;
  const int b   = blockIdx.z;
  const int c0  = blockIdx.y * 64;
  const int hw0 = blockIdx.x * 64;
  const float* xp = x + ((size_t)b * 2048 + c0) * 1024 + hw0;
#pragma unroll
  for (int i = 0; i < 4; ++i) {
    const int c = i * 16 + ty;
    const float4 v = *(const float4*)(xp + (size_t)c * 1024 + tx * 4);
    tile[c][tx * 4 + 0] = v.x; tile[c][tx * 4 + 1] = v.y;
    tile[c][tx * 4 + 2] = v.z; tile[c][tx * 4 + 3] = v.w;
  }
  __syncthreads();
  bf16* op = xb + ((size_t)b * 1024 + hw0) * 2048 + c0;
#pragma unroll
  for (int i = 0; i < 4; ++i) {
    const int hw = i * 16 + ty;
    bf16x4 o;
    o[0] = (bf16)tile[tx * 4 + 0][hw];
    o[1] = (bf16)tile[tx * 4 + 1][hw];
    o[2] = (bf16)tile[tx * 4 + 2][hw];
    o[3] = (bf16)tile[tx * 4 + 3][hw];
    *(bf16x4*)(op + (size_t)hw * 2048 + tx * 4) = o;
  }
}

// ---------------- GEMM1: hb[M,1024] = xb[M,2048] . w1b^T, fused BN-stats partials ----------------
// 128x128 tile, BK=64, XOR-swizzled LDS (conflict-free), XCD-aware block mapping:
// xcd = id&7; within an XCD bn iterates fastest so the 8 blocks sharing an A-tile
// are temporally adjacent on the SAME XCD -> A fetched ~once from HBM.
__global__ __launch_bounds__(256, 4)
void gemm1(const bf16* __restrict__ A, const bf16* __restrict__ Bt,
           bf16* __restrict__ Cb, float* __restrict__ S1, float* __restrict__ S2) {
  __shared__ __align__(16) bf16 As[128 * 64];
  __shared__ __align__(16) bf16 Bs[128 * 64];
  const int K = 2048, N = 1024;
  const int tid  = threadIdx.x;
  const int wave = tid >> 6;
  const int lane = tid & 63;
  const int id = blockIdx.x;                 // 2048 blocks
  const int bm = (id & 7) * 32 + ((id >> 3) >> 3);
  const int bn = (id >> 3) & 7;
  const int wr = wave >> 1, wc = wave & 1;
  const int srow = lane >> 3;
  const int scol = (lane & 7) ^ srow;        // staged (swizzled) source chunk

  f32x4 acc[4][4];
#pragma unroll
  for (int r = 0; r < 4; ++r)
#pragma unroll
    for (int c = 0; c < 4; ++c) acc[r][c] = (f32x4){0.f, 0.f, 0.f, 0.f};

  const bf16* Ag = A + (size_t)(bm * 128) * K;
  const bf16* Bg = Bt + (size_t)(bn * 128) * K;

  const int mrow = lane & 15;
  const int kq = lane >> 4;
  const int sw = mrow & 7;
  const bf16* Asw = As + (wr * 64) * 64;
  const bf16* Bsw = Bs + (wc * 64) * 64;

  for (int k0 = 0; k0 < K; k0 += 64) {
#pragma unroll
    for (int j = 0; j < 4; ++j) {
      const int row = j * 32 + wave * 8;
      async_copy16((void*)(As + row * 64),
                   (const void*)(Ag + (size_t)(row + srow) * K + k0 + scol * 8));
      async_copy16((void*)(Bs + row * 64),
                   (const void*)(Bg + (size_t)(row + srow) * K + k0 + scol * 8));
    }
    __syncthreads();
#pragma unroll
    for (int kk = 0; kk < 2; ++kk) {
      bf16x8 af[4], bfr[4];
      const int lc = kk * 4 + kq;
#pragma unroll
      for (int r = 0; r < 4; ++r)
        af[r] = *(const bf16x8*)(Asw + (r * 16 + mrow) * 64 + ((lc ^ sw) * 8));
#pragma unroll
      for (int c = 0; c < 4; ++c)
        bfr[c] = *(const bf16x8*)(Bsw + (c * 16 + mrow) * 64 + ((lc ^ sw) * 8));
#pragma unroll
      for (int r = 0; r < 4; ++r)
#pragma unroll
        for (int c = 0; c < 4; ++c)
          acc[r][c] = __builtin_amdgcn_mfma_f32_16x16x32_bf16(af[r], bfr[c], acc[r][c], 0, 0, 0);
    }
    __syncthreads();
  }

  // C/D layout: col = lane&15, row = (lane>>4)*4 + reg
  const int crow = (lane >> 4) * 4;
  const int ccol = lane & 15;
#pragma unroll
  for (int r = 0; r < 4; ++r)
#pragma unroll
    for (int c = 0; c < 4; ++c)
#pragma unroll
      for (int i = 0; i < 4; ++i) {
        const int gm = bm * 128 + wr * 64 + r * 16 + crow + i;
        const int gn = bn * 128 + wc * 64 + c * 16 + ccol;
        Cb[(size_t)gm * N + gn] = (bf16)acc[r][c][i];
      }

  // Fused BN-stats partials: per-column sum/sumsq over this block's 128 rows.
  float s1[4], s2[4];
#pragma unroll
  for (int c = 0; c < 4; ++c) {
    float a = 0.f, b = 0.f;
#pragma unroll
    for (int r = 0; r < 4; ++r)
#pragma unroll
      for (int i = 0; i < 4; ++i) { const float v = acc[r][c][i]; a += v; b += v * v; }
    // reduce over row-quadrant lanes (same ccol, different lane>>4)
#pragma unroll
    for (int msk = 16; msk < 64; msk <<= 1) { a += __shfl_xor(a, msk, 64); b += __shfl_xor(b, msk, 64); }
    s1[c] = a; s2[c] = b;
  }
  float* S1s = (float*)As;        // [2][128]
  float* S2s = S1s + 256;         // [2][128]
  if ((lane & 15) == lane) {      // lanes 0..15 of each wave
#pragma unroll
    for (int c = 0; c < 4; ++c) {
      S1s[wr * 128 + wc * 64 + c * 16 + lane] = s1[c];
      S2s[wr * 128 + wc * 64 + c * 16 + lane] = s2[c];
    }
  }
  __syncthreads();
  if (tid < 128) {
    atomicAdd(&S1[bn * 128 + tid], S1s[tid] + S1s[128 + tid]);
    atomicAdd(&S2[bn * 128 + tid], S2s[tid] + S2s[128 + tid]);
  }
}

// ---------------- GEMM2 fused v2: BN-finalize + f = relu(hb*scale+shift).w2b^T + row-L2-norm + g ----
// 256 threads (4 waves), tile 64m x 256n, BK=64, grid 512 = 2 blocks/CU (inter-block overlap
// hides the per-K-step barrier drain that 1-block/CU could not). BN finalize fused into the
// prologue: every block computes all 1024 scale/shift into LDS (1 float4/thread) -- removes
// the bn_finalize kernel AND turns the in-loop scale/shift loads into broadcast ds_read_b128.
__global__ __launch_bounds__(256, 2)
void gemm2f(const bf16* __restrict__ A, const bf16* __restrict__ Bt,
            const float* __restrict__ S1, const float* __restrict__ S2,
            const float* __restrict__ gamma, const float* __restrict__ beta,
            float* __restrict__ g) {
  __shared__ __align__(16) bf16 As[64 * 64];     //  8 KiB
  __shared__ __align__(16) bf16 Bs[256 * 64];    // 32 KiB
  __shared__ __align__(16) float scale_s[1024];  //  4 KiB
  __shared__ __align__(16) float shift_s[1024];  //  4 KiB
  const int K = 1024;
  const int tid  = threadIdx.x;
  const int wave = tid >> 6;                 // == wc, 4 waves, wave tile 64m x 64n
  const int lane = tid & 63;
  const int bm = blockIdx.x;                 // 512 blocks, 64-row tiles
  const int wc = wave;
  const int srow = lane >> 3;
  const int scol = (lane & 7) ^ srow;

  // ---- fused BN finalize: 4 channels per thread ----
  {
    const float inv_n = 1.0f / 32768.0f;
    const float4 s1 = ((const float4*)S1)[tid];
    const float4 s2 = ((const float4*)S2)[tid];
    const float4 ga = ((const float4*)gamma)[tid];
    const float4 be = ((const float4*)beta)[tid];
    float4 sc, sh;
    float m, v, rs;
    m = s1.x * inv_n; v = s2.x * inv_n - m * m; rs = rsqrtf(v + 1e-5f); sc.x = ga.x * rs; sh.x = be.x - m * sc.x;
    m = s1.y * inv_n; v = s2.y * inv_n - m * m; rs = rsqrtf(v + 1e-5f); sc.y = ga.y * rs; sh.y = be.y - m * sc.y;
    m = s1.z * inv_n; v = s2.z * inv_n - m * m; rs = rsqrtf(v + 1e-5f); sc.z = ga.z * rs; sh.z = be.z - m * sc.z;
    m = s1.w * inv_n; v = s2.w * inv_n - m * m; rs = rsqrtf(v + 1e-5f); sc.w = ga.w * rs; sh.w = be.w - m * sc.w;
    ((float4*)scale_s)[tid] = sc;
    ((float4*)shift_s)[tid] = sh;
  }

  f32x4 acc[4][4];
#pragma unroll
  for (int r = 0; r < 4; ++r)
#pragma unroll
    for (int c = 0; c < 4; ++c) acc[r][c] = (f32x4){0.f, 0.f, 0.f, 0.f};

  const bf16* Ag = A + (size_t)(bm * 64) * K;

  const int mrow = lane & 15;
  const int kq = lane >> 4;
  const int sw = mrow & 7;
  const bf16* Bsw = Bs + (wc * 64) * 64;

  for (int k0 = 0; k0 < K; k0 += 64) {
    // stage A: 64 rows (2 async/thread), B: 256 rows (8 async/thread)
#pragma unroll
    for (int j = 0; j < 2; ++j) {
      const int row = j * 32 + wave * 8;
      async_copy16((void*)(As + row * 64),
                   (const void*)(Ag + (size_t)(row + srow) * K + k0 + scol * 8));
    }
#pragma unroll
    for (int j = 0; j < 8; ++j) {
      const int row = j * 32 + wave * 8;
      async_copy16((void*)(Bs + row * 64),
                   (const void*)(Bt + (size_t)(row + srow) * K + k0 + scol * 8));
    }
    __syncthreads();
#pragma unroll
    for (int kk = 0; kk < 2; ++kk) {
      const int lc = kk * 4 + kq;
      const int kbase = k0 + lc * 8;
      const float4 sc0 = *(const float4*)(scale_s + kbase);      // broadcast ds_read_b128
      const float4 sc1 = *(const float4*)(scale_s + kbase + 4);
      const float4 sh0 = *(const float4*)(shift_s + kbase);
      const float4 sh1 = *(const float4*)(shift_s + kbase + 4);
      const float scv[8] = {sc0.x, sc0.y, sc0.z, sc0.w, sc1.x, sc1.y, sc1.z, sc1.w};
      const float shv[8] = {sh0.x, sh0.y, sh0.z, sh0.w, sh1.x, sh1.y, sh1.z, sh1.w};
      bf16x8 af[4], bfr[4];
#pragma unroll
      for (int r = 0; r < 4; ++r) {
        bf16x8 a = *(const bf16x8*)(As + (r * 16 + mrow) * 64 + ((lc ^ sw) * 8));
#pragma unroll
        for (int j = 0; j < 8; ++j)
          a[j] = (bf16)fmaxf(0.f, fmaf((float)a[j], scv[j], shv[j]));
        af[r] = a;
      }
#pragma unroll
      for (int c = 0; c < 4; ++c)
        bfr[c] = *(const bf16x8*)(Bsw + (c * 16 + mrow) * 64 + ((lc ^ sw) * 8));
#pragma unroll
      for (int r = 0; r < 4; ++r)
#pragma unroll
        for (int c = 0; c < 4; ++c)
          acc[r][c] = __builtin_amdgcn_mfma_f32_16x16x32_bf16(af[r], bfr[c], acc[r][c], 0, 0, 0);
    }
    __syncthreads();
  }

  // ---- epilogue: row L2 norms over 64 rows x 256 cols + g accumulation ----
  float* ss4   = (float*)As;      // [4 wc][64 rows]
  float* inv_s = ss4 + 256;       // [64]
  const int q = lane >> 4;
  // (a) per-row sum of squares over this wave's 64 cols
#pragma unroll
  for (int r = 0; r < 4; ++r) {
    float ssv[4];
#pragma unroll
    for (int i = 0; i < 4; ++i) {
      float s = 0.f;
#pragma unroll
      for (int c = 0; c < 4; ++c) { const float v = acc[r][c][i]; s += v * v; }
#pragma unroll
      for (int msk = 1; msk < 16; msk <<= 1) s += __shfl_xor(s, msk, 64);
      ssv[i] = s;
    }
    if ((lane & 15) == 0)
#pragma unroll
      for (int i = 0; i < 4; ++i)
        ss4[wc * 64 + r * 16 + q * 4 + i] = ssv[i];
  }
  __syncthreads();
  if (tid < 64) {
    const float rs = ss4[tid] + ss4[64 + tid] + ss4[128 + tid] + ss4[192 + tid];
    inv_s[tid] = 1.0f / fmaxf(sqrtf(rs), 1e-12f);
  }
  __syncthreads();
  // (b) g[b][col] += sum over rows of f*inv
  const int b = bm >> 4;          // 16 tiles of 64 rows per batch image
  const int ccol = lane & 15;
#pragma unroll
  for (int c = 0; c < 4; ++c) {
    float gl = 0.f;
#pragma unroll
    for (int r = 0; r < 4; ++r)
#pragma unroll
      for (int i = 0; i < 4; ++i)
        gl += acc[r][c][i] * inv_s[r * 16 + q * 4 + i];
#pragma unroll
    for (int msk = 16; msk < 64; msk <<= 1) gl += __shfl_xor(gl, msk, 64);
    if ((lane & 48) == 0)
      atomicAdd(&g[b * 256 + wc * 64 + c * 16 + ccol], gl);
  }
}

// ---------------- normalize prototypes + sim = g . p_norm^T ----------------
__global__ __launch_bounds__(256)
void sim_kernel(const float* __restrict__ g, const float* __restrict__ protos,
                float* __restrict__ out) {
  const int wave = threadIdx.x >> 6, lane = threadIdx.x & 63;
  const int n = blockIdx.x * 4 + wave;  // 1000 prototypes, grid 250
  const float4 p = *(const float4*)(protos + (size_t)n * 256 + lane * 4);
  float ss = p.x * p.x + p.y * p.y + p.z * p.z + p.w * p.w;
#pragma unroll
  for (int msk = 1; msk < 64; msk <<= 1) ss += __shfl_xor(ss, msk, 64);
  const float inv = 1.0f / fmaxf(sqrtf(ss), 1e-12f);
  const float px = p.x * inv, py = p.y * inv, pz = p.z * inv, pw = p.w * inv;
  for (int b = 0; b < 32; ++b) {
    const float4 gv = *(const float4*)(g + b * 256 + lane * 4);
    float d = px * gv.x + py * gv.y + pz * gv.z + pw * gv.w;
#pragma unroll
    for (int msk = 1; msk < 64; msk <<= 1) d += __shfl_xor(d, msk, 64);
    if (lane == 0) out[b * 1000 + n] = d;
  }
}

extern "C" void kernel_launch(void* const* d_in, const int* in_sizes, int n_in,
                              void* d_out, int out_size, void* d_ws, size_t ws_size,
                              hipStream_t stream) {
  const float* x      = (const float*)d_in[0];  // [32,2048,32,32]
  const float* w1     = (const float*)d_in[1];  // [1024,2048]
  const float* gamma  = (const float*)d_in[2];  // [1024]
  const float* beta   = (const float*)d_in[3];  // [1024]
  const float* w2     = (const float*)d_in[4];  // [256,1024]
  const float* protos = (const float*)d_in[5];  // [1000,256]
  float* out = (float*)d_out;                   // [32,1000]

  char* ws = (char*)d_ws;
  // layout (bytes):
  //   0         : xb  [32768,2048] bf16  (128 MiB)
  //   128 MiB   : hb  [32768,1024] bf16  ( 64 MiB)
  //   192 MiB   : w1b (4 MiB), w2b (0.5 MiB)
  //   then      : S1(4K) S2(4K) g(32K)
  bf16*  xb    = (bf16*)(ws);
  bf16*  hb    = (bf16*)(ws + (size_t)134217728);
  bf16*  w1b   = (bf16*)(ws + (size_t)201326592);
  bf16*  w2b   = (bf16*)(ws + (size_t)205520896);
  float* S1    = (float*)(ws + (size_t)206045184);
  float* S2    = (float*)(ws + (size_t)206049280);
  float* g     = (float*)(ws + (size_t)206053376);

  hipMemsetAsync(S1, 0, 40960, stream);  // S1 + S2 + g contiguous

  f2bf_kernel<<<2048, 256, 0, stream>>>(w1, w1b, 524288);
  f2bf_kernel<<<256, 256, 0, stream>>>(w2, w2b, 65536);
  transpose_convert<<<dim3(16, 32, 32), 256, 0, stream>>>(x, xb);
  gemm1<<<2048, 256, 0, stream>>>(xb, w1b, hb, S1, S2);
  gemm2f<<<512, 256, 0, stream>>>(hb, w2b, S1, S2, gamma, beta, g);
  sim_kernel<<<250, 256, 0, stream>>>(g, protos, out);
}